// Round 10
// baseline (262.309 us; speedup 1.0000x reference)
//
#include <hip/hip_runtime.h>
#include <hip/hip_bf16.h>

#define FDIM 128
#define NRBF 20
#define PI_OVER_CUT 0.6283185307179586f  // pi / 5.0

// weight-conversion element counts (prep_kernel block split)
#define WCONV_ELEMS (128 * 128 + 256 * 128 + 256 * 32)   // 57344
#define WCONV_BLOCKS (WCONV_ELEMS / 256)                 // 224

typedef short bf8_t __attribute__((ext_vector_type(8)));   // 8 bf16 (4 VGPRs)
typedef float f4_t  __attribute__((ext_vector_type(4)));   // 4 fp32 acc
typedef unsigned short us8_t __attribute__((ext_vector_type(8))); // 16B load unit

static __device__ __forceinline__ unsigned short bf16_bits(float x) {
    unsigned u = __float_as_uint(x);
    unsigned r = u + 0x7FFF + ((u >> 16) & 1);   // round-to-nearest-even
    return (unsigned short)(r >> 16);
}
static __device__ __forceinline__ float bf16_f(unsigned short b) {
    return __uint_as_float(((unsigned)b) << 16);
}

// ---- prep: weight conversion (blocks [0,224)) + dst histogram (rest) ------
__global__ __launch_bounds__(256) void prep_kernel(
    const float* __restrict__ W1, const float* __restrict__ W2,
    const float* __restrict__ Wf,
    unsigned short* __restrict__ W1T, unsigned short* __restrict__ W2T,
    unsigned short* __restrict__ WfT,
    const int* __restrict__ edge, int* __restrict__ counts, int E)
{
    int b = blockIdx.x;
    if (b < WCONV_BLOCKS) {
        int i = b * 256 + threadIdx.x;
        if (i < 128 * 128) {
            int n = i >> 7, k = i & 127;
            W1T[n * 128 + k] = bf16_bits(W1[k * 128 + n]);
        } else if (i < 128 * 128 + 256 * 128) {
            int j = i - 128 * 128;
            int n = j >> 7, k = j & 127;
            int col = (n < 128) ? n : n + 128;
            W2T[n * 128 + k] = bf16_bits(W2[k * 384 + col]);
        } else {
            int j = i - (128 * 128 + 256 * 128);
            int n = j >> 5, k = j & 31;
            int col = (n < 128) ? n : n + 128;
            WfT[n * 32 + k] = (k < NRBF) ? bf16_bits(Wf[k * 384 + col])
                                         : (unsigned short)0;
        }
    } else {
        int i = (b - WCONV_BLOCKS) * 256 + threadIdx.x;
        if (i < E) atomicAdd(&counts[edge[2 * i]], 1);
    }
}

// ---- fused: node MLP/filter/VM pack (blocks [0,nfb)) + scan (block nfb) ---
// Scan rides free: it runs on 1 CU while 1250 node blocks occupy the rest.
__global__ __launch_bounds__(256) void node_fused(
    const float* __restrict__ S, const float* __restrict__ node_vec,
    const float* __restrict__ edge_dis,
    const unsigned short* __restrict__ W1T, const float* __restrict__ b1,
    const unsigned short* __restrict__ W2T, const float* __restrict__ b2,
    const unsigned short* __restrict__ WfT, const float* __restrict__ bfv,
    ushort4* __restrict__ VM,
    const int* __restrict__ counts, int* __restrict__ offsets,
    int* __restrict__ cursor, int nf_blocks, int N)
{
    __shared__ __align__(16) unsigned short sh_s[16][136];
    __shared__ __align__(16) unsigned short sh_h[16][136];
    __shared__ __align__(16) unsigned short sh_rbf[16][40];
    __shared__ float sh_ccut[16];
    __shared__ int sh_scan[256];

    const int tid = threadIdx.x;

    // ---------------- scan block ----------------
    if (blockIdx.x == nf_blocks) {
        const int chunk = (N + 255) / 256;
        const int beg = tid * chunk, end = min(beg + chunk, N);
        int local = 0;
        for (int i = beg; i < end; i++) local += counts[i];
        sh_scan[tid] = local;
        __syncthreads();
        for (int off = 1; off < 256; off <<= 1) {
            int v = (tid >= off) ? sh_scan[tid - off] : 0;
            __syncthreads();
            sh_scan[tid] += v;
            __syncthreads();
        }
        int run = sh_scan[tid] - local;
        for (int i = beg; i < end; i++) {
            offsets[i] = run;
            cursor[i] = run;
            run += counts[i];
        }
        if (tid == 255) offsets[N] = sh_scan[255];
        return;
    }

    // ---------------- node blocks ----------------
    const int lane = tid & 63;
    const int wave = tid >> 6;      // 0..3: column quarter
    const int l15  = lane & 15;
    const int quad = lane >> 4;
    const int m0   = blockIdx.x * 16;

    for (int t = tid; t < 16 * 32; t += 256) {          // node_s: 512 float4
        int row = t >> 5, c4 = (t & 31) * 4;
        int n = m0 + row; if (n >= N) n = N - 1;
        float4 x = *(const float4*)(S + (size_t)n * FDIM + c4);
        ushort4 u;
        u.x = bf16_bits(x.x); u.y = bf16_bits(x.y);
        u.z = bf16_bits(x.z); u.w = bf16_bits(x.w);
        *(ushort4*)&sh_s[row][c4] = u;
    }
    if (tid < 16 * 8) {                                  // rbf
        int row = tid >> 3, k0 = (tid & 7) * 4;
        int n = m0 + row; if (n >= N) n = N - 1;
        float dd = edge_dis[n];
        float ph = PI_OVER_CUT * dd;
        float inv = 1.0f / dd;
        ushort4 u;
        u.x = (k0 + 0 < NRBF) ? bf16_bits(sinf((float)(k0 + 1) * ph) * inv) : 0;
        u.y = (k0 + 1 < NRBF) ? bf16_bits(sinf((float)(k0 + 2) * ph) * inv) : 0;
        u.z = (k0 + 2 < NRBF) ? bf16_bits(sinf((float)(k0 + 3) * ph) * inv) : 0;
        u.w = (k0 + 3 < NRBF) ? bf16_bits(sinf((float)(k0 + 4) * ph) * inv) : 0;
        *(ushort4*)&sh_rbf[row][k0] = u;
    }
    if (tid < 16) {
        int n = m0 + tid; if (n >= N) n = N - 1;
        float dd = edge_dis[n];
        sh_ccut[tid] = (dd <= 5.0f) ? 0.5f * (cosf(PI_OVER_CUT * dd) + 1.0f) : 0.0f;
    }
    __syncthreads();

    // phase 1: GEMM1 + silu -> sh_h
    {
        bf8_t a1[4];
        #pragma unroll
        for (int kk = 0; kk < 4; kk++)
            a1[kk] = *(const bf8_t*)&sh_s[l15][kk * 32 + quad * 8];

        #pragma unroll
        for (int i = 0; i < 2; i++) {
            int col = (wave * 2 + i) * 16 + l15;
            const unsigned short* wp = W1T + (size_t)col * FDIM + quad * 8;
            f4_t acc = {0.f, 0.f, 0.f, 0.f};
            #pragma unroll
            for (int kk = 0; kk < 4; kk++) {
                bf8_t b = *(const bf8_t*)(wp + kk * 32);
                acc = __builtin_amdgcn_mfma_f32_16x16x32_bf16(a1[kk], b, acc, 0, 0, 0);
            }
            float bb = b1[col];
            #pragma unroll
            for (int r = 0; r < 4; r++) {
                float x = acc[r] + bb;
                x = x / (1.f + expf(-x));
                sh_h[quad * 4 + r][col] = bf16_bits(x);
            }
        }
    }
    __syncthreads();

    // phase 2: GEMM2 + filter GEMM + epilogue
    bf8_t a2[4], af;
    #pragma unroll
    for (int kk = 0; kk < 4; kk++)
        a2[kk] = *(const bf8_t*)&sh_h[l15][kk * 32 + quad * 8];
    af = *(const bf8_t*)&sh_rbf[l15][quad * 8];

    #pragma unroll
    for (int i = 0; i < 2; i++) {
        int pc = (wave * 2 + i) * 16 + l15;
        const unsigned short* wg = W2T + (size_t)pc * FDIM + quad * 8;
        const unsigned short* wm = W2T + (size_t)(pc + 128) * FDIM + quad * 8;
        f4_t ag = {0.f, 0.f, 0.f, 0.f}, am = {0.f, 0.f, 0.f, 0.f};
        #pragma unroll
        for (int kk = 0; kk < 4; kk++) {
            bf8_t bg = *(const bf8_t*)(wg + kk * 32);
            bf8_t bm = *(const bf8_t*)(wm + kk * 32);
            ag = __builtin_amdgcn_mfma_f32_16x16x32_bf16(a2[kk], bg, ag, 0, 0, 0);
            am = __builtin_amdgcn_mfma_f32_16x16x32_bf16(a2[kk], bm, am, 0, 0, 0);
        }
        f4_t fg = {0.f, 0.f, 0.f, 0.f}, fm = {0.f, 0.f, 0.f, 0.f};
        {
            bf8_t bg = *(const bf8_t*)(WfT + (size_t)pc * 32 + quad * 8);
            bf8_t bm = *(const bf8_t*)(WfT + (size_t)(pc + 128) * 32 + quad * 8);
            fg = __builtin_amdgcn_mfma_f32_16x16x32_bf16(af, bg, fg, 0, 0, 0);
            fm = __builtin_amdgcn_mfma_f32_16x16x32_bf16(af, bm, fm, 0, 0, 0);
        }

        float b2g = b2[pc], b2m = b2[256 + pc];
        float bfg = bfv[pc], bfm = bfv[256 + pc];
        #pragma unroll
        for (int r = 0; r < 4; r++) {
            int lrow = quad * 4 + r;
            int n = m0 + lrow;
            if (n < N) {
                float cc = sh_ccut[lrow];
                float a  = (fg[r] + bfg) * cc * (ag[r] + b2g);
                float mv = (fm[r] + bfm) * cc * (am[r] + b2m);
                const float* vp = node_vec + (size_t)n * 384 + 3 * pc;
                ushort4 rec;
                rec.x = bf16_bits(a * vp[0]);
                rec.y = bf16_bits(a * vp[1]);
                rec.z = bf16_bits(a * vp[2]);
                rec.w = bf16_bits(mv);
                VM[(size_t)n * FDIM + pc] = rec;
            }
        }
    }
}

__global__ __launch_bounds__(256) void scatter_kernel(
    const int* __restrict__ edge, int* __restrict__ cursor,
    int* __restrict__ src_sorted, int E)
{
    int i = blockIdx.x * 256 + threadIdx.x;
    if (i >= E) return;
    int d = edge[2 * i];
    int s = edge[2 * i + 1];
    int pos = atomicAdd(&cursor[d], 1);
    src_sorted[pos] = s;
}

// ------- gather: one WAVE per dst; lane owns 2 channels via dwordx4 --------
// Per edge per wave: ONE global_load_dwordx4 instruction fetches the full
// 1 KB VM row (64 lanes x 16 B) -> 2x bytes-in-flight vs the 8 B/lane layout.
__global__ __launch_bounds__(256) void gather_bf16(
    const int* __restrict__ offsets, const int* __restrict__ src_sorted,
    const us8_t* __restrict__ VM8, const float* __restrict__ node_vec,
    const float* __restrict__ node_s,
    float* __restrict__ out_vec, float* __restrict__ out_s, int N)
{
    int d = blockIdx.x * 4 + (threadIdx.x >> 6);
    int lane = threadIdx.x & 63;          // channels 2*lane, 2*lane+1
    if (d >= N) return;

    int beg = offsets[d];
    int end = offsets[d + 1];

    float a0A = 0.f, a1A = 0.f, a2A = 0.f, asA = 0.f;
    float a0B = 0.f, a1B = 0.f, a2B = 0.f, asB = 0.f;

    int j = beg;
    for (; j + 7 < end; j += 8) {
        us8_t r0 = VM8[(size_t)src_sorted[j]     * 64 + lane];
        us8_t r1 = VM8[(size_t)src_sorted[j + 1] * 64 + lane];
        us8_t r2 = VM8[(size_t)src_sorted[j + 2] * 64 + lane];
        us8_t r3 = VM8[(size_t)src_sorted[j + 3] * 64 + lane];
        us8_t r4 = VM8[(size_t)src_sorted[j + 4] * 64 + lane];
        us8_t r5 = VM8[(size_t)src_sorted[j + 5] * 64 + lane];
        us8_t r6 = VM8[(size_t)src_sorted[j + 6] * 64 + lane];
        us8_t r7 = VM8[(size_t)src_sorted[j + 7] * 64 + lane];
        #define ACC(r) \
            a0A += bf16_f(r[0]); a1A += bf16_f(r[1]); a2A += bf16_f(r[2]); asA += bf16_f(r[3]); \
            a0B += bf16_f(r[4]); a1B += bf16_f(r[5]); a2B += bf16_f(r[6]); asB += bf16_f(r[7]);
        ACC(r0) ACC(r1) ACC(r2) ACC(r3) ACC(r4) ACC(r5) ACC(r6) ACC(r7)
    }
    for (; j + 3 < end; j += 4) {
        us8_t r0 = VM8[(size_t)src_sorted[j]     * 64 + lane];
        us8_t r1 = VM8[(size_t)src_sorted[j + 1] * 64 + lane];
        us8_t r2 = VM8[(size_t)src_sorted[j + 2] * 64 + lane];
        us8_t r3 = VM8[(size_t)src_sorted[j + 3] * 64 + lane];
        ACC(r0) ACC(r1) ACC(r2) ACC(r3)
    }
    for (; j < end; j++) {
        us8_t r = VM8[(size_t)src_sorted[j] * 64 + lane];
        ACC(r)
        #undef ACC
    }

    // epilogue: out = input + acc  (all coalesced)
    {
        const float* sp = node_s + (size_t)d * FDIM + 2 * lane;
        float* op = out_s + (size_t)d * FDIM + 2 * lane;
        float2 ns = *(const float2*)sp;
        float2 r; r.x = ns.x + asA; r.y = ns.y + asB;
        *(float2*)op = r;
    }
    {
        const float* ip = node_vec + (size_t)d * 384 + 6 * lane;
        float* op = out_vec + (size_t)d * 384 + 6 * lane;
        op[0] = ip[0] + a0A;
        op[1] = ip[1] + a1A;
        op[2] = ip[2] + a2A;
        op[3] = ip[3] + a0B;
        op[4] = ip[4] + a1B;
        op[5] = ip[5] + a2B;
    }
}

extern "C" void kernel_launch(void* const* d_in, const int* in_sizes, int n_in,
                              void* d_out, int out_size, void* d_ws, size_t ws_size,
                              hipStream_t stream) {
    const float* node_s   = (const float*)d_in[0];
    const float* node_vec = (const float*)d_in[1];
    const int*   edge     = (const int*)d_in[2];
    const float* edge_dis = (const float*)d_in[4];
    const float* W1 = (const float*)d_in[5];
    const float* b1 = (const float*)d_in[6];
    const float* W2 = (const float*)d_in[7];
    const float* b2 = (const float*)d_in[8];
    const float* Wf = (const float*)d_in[9];
    const float* bf = (const float*)d_in[10];

    const int N = in_sizes[0] / FDIM;
    const int E = in_sizes[2] / 2;

    float* out_vec = (float*)d_out;              // N*128*3
    float* out_s   = out_vec + (size_t)N * 384;  // N*128

    // workspace layout (~22 MB)
    int* counts     = (int*)d_ws;          // N
    int* offsets    = counts + N;          // N+1
    int* cursor     = offsets + N + 1;     // N
    int* src_sorted = cursor + N;          // E
    size_t int_bytes = (((size_t)(3 * N + 1 + E) * 4) + 15) & ~(size_t)15;
    unsigned short* W1T = (unsigned short*)((char*)d_ws + int_bytes);  // 128*128
    unsigned short* W2T = W1T + 128 * 128;                             // 256*128
    unsigned short* WfT = W2T + 256 * 128;                             // 256*32
    ushort4*        VMh = (ushort4*)(WfT + 256 * 32);                  // N*128

    hipMemsetAsync(counts, 0, (size_t)N * sizeof(int), stream);

    const int hist_blocks = (E + 255) / 256;
    prep_kernel<<<WCONV_BLOCKS + hist_blocks, 256, 0, stream>>>(
        W1, W2, Wf, W1T, W2T, WfT, edge, counts, E);

    const int nfb = (N + 15) / 16;
    node_fused<<<nfb + 1, 256, 0, stream>>>(
        node_s, node_vec, edge_dis, W1T, b1, W2T, b2, WfT, bf, VMh,
        counts, offsets, cursor, nfb, N);

    scatter_kernel<<<(E + 255) / 256, 256, 0, stream>>>(edge, cursor, src_sorted, E);

    gather_bf16<<<(N + 3) / 4, 256, 0, stream>>>(
        offsets, src_sorted, (const us8_t*)VMh, node_vec, node_s,
        out_vec, out_s, N);
}

// Round 11
// 246.496 us; speedup vs baseline: 1.0642x; 1.0642x over previous
//
#include <hip/hip_runtime.h>
#include <hip/hip_bf16.h>

#define FDIM 128
#define NRBF 20
#define PI_OVER_CUT 0.6283185307179586f  // pi / 5.0

// weight-conversion element counts (prep_kernel block split)
#define WCONV_ELEMS (128 * 128 + 256 * 128 + 256 * 32)   // 57344
#define WCONV_BLOCKS (WCONV_ELEMS / 256)                 // 224

typedef short bf8_t __attribute__((ext_vector_type(8)));   // 8 bf16 (4 VGPRs)
typedef float f4_t  __attribute__((ext_vector_type(4)));   // 4 fp32 acc
typedef unsigned short us8_t __attribute__((ext_vector_type(8))); // 16B load unit

static __device__ __forceinline__ unsigned short bf16_bits(float x) {
    unsigned u = __float_as_uint(x);
    unsigned r = u + 0x7FFF + ((u >> 16) & 1);   // round-to-nearest-even
    return (unsigned short)(r >> 16);
}
static __device__ __forceinline__ float bf16_f(unsigned short b) {
    return __uint_as_float(((unsigned)b) << 16);
}

// ---- prep: weight conversion (blocks [0,224)) + dst histogram (rest) ------
__global__ __launch_bounds__(256) void prep_kernel(
    const float* __restrict__ W1, const float* __restrict__ W2,
    const float* __restrict__ Wf,
    unsigned short* __restrict__ W1T, unsigned short* __restrict__ W2T,
    unsigned short* __restrict__ WfT,
    const int* __restrict__ edge, int* __restrict__ counts, int E)
{
    int b = blockIdx.x;
    if (b < WCONV_BLOCKS) {
        int i = b * 256 + threadIdx.x;
        if (i < 128 * 128) {
            int n = i >> 7, k = i & 127;
            W1T[n * 128 + k] = bf16_bits(W1[k * 128 + n]);
        } else if (i < 128 * 128 + 256 * 128) {
            int j = i - 128 * 128;
            int n = j >> 7, k = j & 127;
            int col = (n < 128) ? n : n + 128;
            W2T[n * 128 + k] = bf16_bits(W2[k * 384 + col]);
        } else {
            int j = i - (128 * 128 + 256 * 128);
            int n = j >> 5, k = j & 31;
            int col = (n < 128) ? n : n + 128;
            WfT[n * 32 + k] = (k < NRBF) ? bf16_bits(Wf[k * 384 + col])
                                         : (unsigned short)0;
        }
    } else {
        int i = (b - WCONV_BLOCKS) * 256 + threadIdx.x;
        if (i < E) atomicAdd(&counts[edge[2 * i]], 1);
    }
}

// ---- fused per-node kernel: MLP + filter + VM pack ------------------------
// 16 rows/block, 4 waves = column quarters. node_vec staged through LDS
// (row pad 388 floats: 1552B rows stay 16B-aligned; 388 % 32 = 4 banks ->
// quad rows alias at most 2-way, which is free).
__global__ __launch_bounds__(256) void node_fused(
    const float* __restrict__ S, const float* __restrict__ node_vec,
    const float* __restrict__ edge_dis,
    const unsigned short* __restrict__ W1T, const float* __restrict__ b1,
    const unsigned short* __restrict__ W2T, const float* __restrict__ b2,
    const unsigned short* __restrict__ WfT, const float* __restrict__ bfv,
    ushort4* __restrict__ VM, int N)
{
    __shared__ __align__(16) unsigned short sh_s[16][136];
    __shared__ __align__(16) unsigned short sh_h[16][136];
    __shared__ __align__(16) unsigned short sh_rbf[16][40];
    __shared__ __align__(16) float sh_nv[16][388];
    __shared__ float sh_ccut[16];

    const int tid  = threadIdx.x;
    const int lane = tid & 63;
    const int wave = tid >> 6;      // 0..3: column quarter
    const int l15  = lane & 15;
    const int quad = lane >> 4;
    const int m0   = blockIdx.x * 16;

    // ---- phase 0: staging (all coalesced) ----
    for (int t = tid; t < 16 * 32; t += 256) {          // node_s: 512 float4
        int row = t >> 5, c4 = (t & 31) * 4;
        int n = m0 + row; if (n >= N) n = N - 1;
        float4 x = *(const float4*)(S + (size_t)n * FDIM + c4);
        ushort4 u;
        u.x = bf16_bits(x.x); u.y = bf16_bits(x.y);
        u.z = bf16_bits(x.z); u.w = bf16_bits(x.w);
        *(ushort4*)&sh_s[row][c4] = u;
    }
    for (int t = tid; t < 16 * 96; t += 256) {          // node_vec: 1536 float4
        int row = t / 96, i4 = (t % 96) * 4;
        int n = m0 + row; if (n >= N) n = N - 1;
        *(float4*)&sh_nv[row][i4] =
            *(const float4*)(node_vec + (size_t)n * 384 + i4);
    }
    if (tid < 16 * 8) {                                  // rbf
        int row = tid >> 3, k0 = (tid & 7) * 4;
        int n = m0 + row; if (n >= N) n = N - 1;
        float dd = edge_dis[n];
        float ph = PI_OVER_CUT * dd;
        float inv = 1.0f / dd;
        ushort4 u;
        u.x = (k0 + 0 < NRBF) ? bf16_bits(sinf((float)(k0 + 1) * ph) * inv) : 0;
        u.y = (k0 + 1 < NRBF) ? bf16_bits(sinf((float)(k0 + 2) * ph) * inv) : 0;
        u.z = (k0 + 2 < NRBF) ? bf16_bits(sinf((float)(k0 + 3) * ph) * inv) : 0;
        u.w = (k0 + 3 < NRBF) ? bf16_bits(sinf((float)(k0 + 4) * ph) * inv) : 0;
        *(ushort4*)&sh_rbf[row][k0] = u;
    }
    if (tid < 16) {
        int n = m0 + tid; if (n >= N) n = N - 1;
        float dd = edge_dis[n];
        sh_ccut[tid] = (dd <= 5.0f) ? 0.5f * (cosf(PI_OVER_CUT * dd) + 1.0f) : 0.0f;
    }
    __syncthreads();

    // ---- phase 1: GEMM1 + silu -> sh_h ----
    {
        bf8_t a1[4];
        #pragma unroll
        for (int kk = 0; kk < 4; kk++)
            a1[kk] = *(const bf8_t*)&sh_s[l15][kk * 32 + quad * 8];

        #pragma unroll
        for (int i = 0; i < 2; i++) {
            int col = (wave * 2 + i) * 16 + l15;
            const unsigned short* wp = W1T + (size_t)col * FDIM + quad * 8;
            f4_t acc = {0.f, 0.f, 0.f, 0.f};
            #pragma unroll
            for (int kk = 0; kk < 4; kk++) {
                bf8_t b = *(const bf8_t*)(wp + kk * 32);
                acc = __builtin_amdgcn_mfma_f32_16x16x32_bf16(a1[kk], b, acc, 0, 0, 0);
            }
            float bb = b1[col];
            #pragma unroll
            for (int r = 0; r < 4; r++) {
                float x = acc[r] + bb;
                x = x / (1.f + expf(-x));
                sh_h[quad * 4 + r][col] = bf16_bits(x);
            }
        }
    }
    __syncthreads();

    // ---- phase 2: GEMM2 + filter GEMM + epilogue ----
    bf8_t a2[4], af;
    #pragma unroll
    for (int kk = 0; kk < 4; kk++)
        a2[kk] = *(const bf8_t*)&sh_h[l15][kk * 32 + quad * 8];
    af = *(const bf8_t*)&sh_rbf[l15][quad * 8];

    #pragma unroll
    for (int i = 0; i < 2; i++) {
        int pc = (wave * 2 + i) * 16 + l15;
        const unsigned short* wg = W2T + (size_t)pc * FDIM + quad * 8;
        const unsigned short* wm = W2T + (size_t)(pc + 128) * FDIM + quad * 8;
        f4_t ag = {0.f, 0.f, 0.f, 0.f}, am = {0.f, 0.f, 0.f, 0.f};
        #pragma unroll
        for (int kk = 0; kk < 4; kk++) {
            bf8_t bg = *(const bf8_t*)(wg + kk * 32);
            bf8_t bm = *(const bf8_t*)(wm + kk * 32);
            ag = __builtin_amdgcn_mfma_f32_16x16x32_bf16(a2[kk], bg, ag, 0, 0, 0);
            am = __builtin_amdgcn_mfma_f32_16x16x32_bf16(a2[kk], bm, am, 0, 0, 0);
        }
        f4_t fg = {0.f, 0.f, 0.f, 0.f}, fm = {0.f, 0.f, 0.f, 0.f};
        {
            bf8_t bg = *(const bf8_t*)(WfT + (size_t)pc * 32 + quad * 8);
            bf8_t bm = *(const bf8_t*)(WfT + (size_t)(pc + 128) * 32 + quad * 8);
            fg = __builtin_amdgcn_mfma_f32_16x16x32_bf16(af, bg, fg, 0, 0, 0);
            fm = __builtin_amdgcn_mfma_f32_16x16x32_bf16(af, bm, fm, 0, 0, 0);
        }

        float b2g = b2[pc], b2m = b2[256 + pc];
        float bfg = bfv[pc], bfm = bfv[256 + pc];
        #pragma unroll
        for (int r = 0; r < 4; r++) {
            int lrow = quad * 4 + r;
            int n = m0 + lrow;
            if (n < N) {
                float cc = sh_ccut[lrow];
                float a  = (fg[r] + bfg) * cc * (ag[r] + b2g);
                float mv = (fm[r] + bfm) * cc * (am[r] + b2m);
                const float* vp = &sh_nv[lrow][3 * pc];
                ushort4 rec;
                rec.x = bf16_bits(a * vp[0]);
                rec.y = bf16_bits(a * vp[1]);
                rec.z = bf16_bits(a * vp[2]);
                rec.w = bf16_bits(mv);
                VM[(size_t)n * FDIM + pc] = rec;
            }
        }
    }
}

// ---- single-block scan, LDS-staged (coalesced global reads) ---------------
__global__ __launch_bounds__(1024) void scan_kernel(
    const int* __restrict__ counts, int* __restrict__ offsets,
    int* __restrict__ cursor, int N)
{
    __shared__ unsigned short lds_cnt[20000];   // counts fit in 16 bits (deg ~16)
    __shared__ int sh[1024];
    const int t = threadIdx.x;
    const int chunk = (N + 1023) / 1024;
    const int beg = t * chunk, end = min(beg + chunk, N);

    for (int i = t; i < N; i += 1024) lds_cnt[i] = (unsigned short)counts[i];
    __syncthreads();

    int local = 0;
    for (int i = beg; i < end; i++) local += lds_cnt[i];
    sh[t] = local;
    __syncthreads();
    for (int off = 1; off < 1024; off <<= 1) {
        int v = (t >= off) ? sh[t - off] : 0;
        __syncthreads();
        sh[t] += v;
        __syncthreads();
    }
    int run = sh[t] - local;  // exclusive prefix of this chunk
    for (int i = beg; i < end; i++) {
        offsets[i] = run;
        cursor[i] = run;
        run += lds_cnt[i];
    }
    if (t == 1023) offsets[N] = sh[1023];
}

__global__ __launch_bounds__(256) void scatter_kernel(
    const int* __restrict__ edge, int* __restrict__ cursor,
    int* __restrict__ src_sorted, int E)
{
    int i = blockIdx.x * 256 + threadIdx.x;
    if (i >= E) return;
    int d = edge[2 * i];
    int s = edge[2 * i + 1];
    int pos = atomicAdd(&cursor[d], 1);
    src_sorted[pos] = s;
}

// ------- gather: one WAVE per dst; lane owns 2 channels via dwordx4 --------
__global__ __launch_bounds__(256) void gather_bf16(
    const int* __restrict__ offsets, const int* __restrict__ src_sorted,
    const us8_t* __restrict__ VM8, const float* __restrict__ node_vec,
    const float* __restrict__ node_s,
    float* __restrict__ out_vec, float* __restrict__ out_s, int N)
{
    int d = blockIdx.x * 4 + (threadIdx.x >> 6);
    int lane = threadIdx.x & 63;          // channels 2*lane, 2*lane+1
    if (d >= N) return;

    int beg = offsets[d];
    int end = offsets[d + 1];

    float a0A = 0.f, a1A = 0.f, a2A = 0.f, asA = 0.f;
    float a0B = 0.f, a1B = 0.f, a2B = 0.f, asB = 0.f;

    int j = beg;
    for (; j + 7 < end; j += 8) {
        us8_t r0 = VM8[(size_t)src_sorted[j]     * 64 + lane];
        us8_t r1 = VM8[(size_t)src_sorted[j + 1] * 64 + lane];
        us8_t r2 = VM8[(size_t)src_sorted[j + 2] * 64 + lane];
        us8_t r3 = VM8[(size_t)src_sorted[j + 3] * 64 + lane];
        us8_t r4 = VM8[(size_t)src_sorted[j + 4] * 64 + lane];
        us8_t r5 = VM8[(size_t)src_sorted[j + 5] * 64 + lane];
        us8_t r6 = VM8[(size_t)src_sorted[j + 6] * 64 + lane];
        us8_t r7 = VM8[(size_t)src_sorted[j + 7] * 64 + lane];
        #define ACC(r) \
            a0A += bf16_f(r[0]); a1A += bf16_f(r[1]); a2A += bf16_f(r[2]); asA += bf16_f(r[3]); \
            a0B += bf16_f(r[4]); a1B += bf16_f(r[5]); a2B += bf16_f(r[6]); asB += bf16_f(r[7]);
        ACC(r0) ACC(r1) ACC(r2) ACC(r3) ACC(r4) ACC(r5) ACC(r6) ACC(r7)
    }
    for (; j + 3 < end; j += 4) {
        us8_t r0 = VM8[(size_t)src_sorted[j]     * 64 + lane];
        us8_t r1 = VM8[(size_t)src_sorted[j + 1] * 64 + lane];
        us8_t r2 = VM8[(size_t)src_sorted[j + 2] * 64 + lane];
        us8_t r3 = VM8[(size_t)src_sorted[j + 3] * 64 + lane];
        ACC(r0) ACC(r1) ACC(r2) ACC(r3)
    }
    for (; j < end; j++) {
        us8_t r = VM8[(size_t)src_sorted[j] * 64 + lane];
        ACC(r)
        #undef ACC
    }

    // epilogue: out = input + acc  (all coalesced)
    {
        const float* sp = node_s + (size_t)d * FDIM + 2 * lane;
        float* op = out_s + (size_t)d * FDIM + 2 * lane;
        float2 ns = *(const float2*)sp;
        float2 r; r.x = ns.x + asA; r.y = ns.y + asB;
        *(float2*)op = r;
    }
    {
        const float* ip = node_vec + (size_t)d * 384 + 6 * lane;
        float* op = out_vec + (size_t)d * 384 + 6 * lane;
        op[0] = ip[0] + a0A;
        op[1] = ip[1] + a1A;
        op[2] = ip[2] + a2A;
        op[3] = ip[3] + a0B;
        op[4] = ip[4] + a1B;
        op[5] = ip[5] + a2B;
    }
}

extern "C" void kernel_launch(void* const* d_in, const int* in_sizes, int n_in,
                              void* d_out, int out_size, void* d_ws, size_t ws_size,
                              hipStream_t stream) {
    const float* node_s   = (const float*)d_in[0];
    const float* node_vec = (const float*)d_in[1];
    const int*   edge     = (const int*)d_in[2];
    const float* edge_dis = (const float*)d_in[4];
    const float* W1 = (const float*)d_in[5];
    const float* b1 = (const float*)d_in[6];
    const float* W2 = (const float*)d_in[7];
    const float* b2 = (const float*)d_in[8];
    const float* Wf = (const float*)d_in[9];
    const float* bf = (const float*)d_in[10];

    const int N = in_sizes[0] / FDIM;
    const int E = in_sizes[2] / 2;

    float* out_vec = (float*)d_out;              // N*128*3
    float* out_s   = out_vec + (size_t)N * 384;  // N*128

    // workspace layout (~22 MB)
    int* counts     = (int*)d_ws;          // N
    int* offsets    = counts + N;          // N+1
    int* cursor     = offsets + N + 1;     // N
    int* src_sorted = cursor + N;          // E
    size_t int_bytes = (((size_t)(3 * N + 1 + E) * 4) + 15) & ~(size_t)15;
    unsigned short* W1T = (unsigned short*)((char*)d_ws + int_bytes);  // 128*128
    unsigned short* W2T = W1T + 128 * 128;                             // 256*128
    unsigned short* WfT = W2T + 256 * 128;                             // 256*32
    ushort4*        VMh = (ushort4*)(WfT + 256 * 32);                  // N*128

    hipMemsetAsync(counts, 0, (size_t)N * sizeof(int), stream);

    const int hist_blocks = (E + 255) / 256;
    prep_kernel<<<WCONV_BLOCKS + hist_blocks, 256, 0, stream>>>(
        W1, W2, Wf, W1T, W2T, WfT, edge, counts, E);

    scan_kernel<<<1, 1024, 0, stream>>>(counts, offsets, cursor, N);

    node_fused<<<(N + 15) / 16, 256, 0, stream>>>(
        node_s, node_vec, edge_dis, W1T, b1, W2T, b2, WfT, bf, VMh, N);

    scatter_kernel<<<(E + 255) / 256, 256, 0, stream>>>(edge, cursor, src_sorted, E);

    gather_bf16<<<(N + 3) / 4, 256, 0, stream>>>(
        offsets, src_sorted, (const us8_t*)VMh, node_vec, node_s,
        out_vec, out_s, N);
}